// Round 10
// baseline (149.392 us; speedup 1.0000x reference)
//
#include <hip/hip_runtime.h>

// out = F_amp(MLP(z_i, z_j, sep_xy2)) * (dxy / sep_r2)
// R3's winning structure (element-axis f32x2 packing, compiler-scheduled
// v_pk_fma_f32), but TWO independent pairs per thread with all 6 float4
// loads issued up front: second pair's loads are in flight during the
// first pair's ~2300-cycle compute -> raises load-latency duty cycle.
// No arrays (fully scalarized), no asm, no LDS, no scalar-path tricks.

typedef float f32x4 __attribute__((ext_vector_type(4)));
typedef float f32x2 __attribute__((ext_vector_type(2)));

__device__ __forceinline__ f32x2 sp(float w) { return (f32x2){w, w}; }

__device__ __forceinline__ f32x2 fma2(f32x2 a, f32x2 b, f32x2 c) {
    return __builtin_elementwise_fma(a, b, c);
}

__device__ __forceinline__ f32x2 lrelu2(f32x2 x) {
    return __builtin_elementwise_max(x, x * 0.1f);   // alpha=0.1
}

__device__ __forceinline__ float tanh_fast(float x) {
    // tanh(x) = 1 - 2/(exp2(2log2e*x)+1); exp+rcp on trans pipe, exact limits
    float e = __builtin_amdgcn_exp2f(x * 2.8853900817779268f);
    return fmaf(-2.0f, __builtin_amdgcn_rcpf(e + 1.0f), 1.0f);
}

__device__ __forceinline__ f32x2 tanh2(f32x2 a) {
    return (f32x2){tanh_fast(a[0]), tanh_fast(a[1])};
}

// One pair (2 elements packed in f32x2 lanes): 3 float4 -> 1 float4
__device__ __forceinline__ f32x4 mlp_pair(
    f32x4 A, f32x4 B, f32x4 C,
    const float* __restrict__ W1, const float* __restrict__ b1,
    const float* __restrict__ W2, const float* __restrict__ b2,
    const float* __restrict__ W3, const float* __restrict__ b3,
    const float* __restrict__ W4, const float* __restrict__ b4)
{
    // element0 = {A0 A1 A2 A3 B0 B1}, element1 = {B2 B3 C0 C1 C2 C3}
    f32x2 px0 = {A[0], B[2]}, py0 = {A[1], B[3]}, pz0 = {A[2], C[0]};
    f32x2 px1 = {A[3], C[1]}, py1 = {B[0], C[2]}, pz1 = {B[1], C[3]};

    f32x2 dx = px1 - px0;
    f32x2 dy = py1 - py0;
    f32x2 dz = pz1 - pz0;
    f32x2 sep_xy2 = fma2(dx, dx, dy * dy);
    f32x2 sep_r2  = fma2(dz, dz, sep_xy2);
    f32x2 inv_r2  = {__builtin_amdgcn_rcpf(sep_r2[0]),
                     __builtin_amdgcn_rcpf(sep_r2[1])};

    f32x2 Z0 = pz0, Z1 = pz1, Z2 = sep_xy2;

    // Layer 1: [3] -> [10], leaky relu
    f32x2 h1[10];
    #pragma unroll
    for (int j = 0; j < 10; ++j) {
        f32x2 a = sp(b1[j]);
        a = fma2(Z0, sp(W1[0 * 10 + j]), a);
        a = fma2(Z1, sp(W1[1 * 10 + j]), a);
        a = fma2(Z2, sp(W1[2 * 10 + j]), a);
        h1[j] = lrelu2(a);
    }

    // Layer 2: [10] -> [10], tanh
    f32x2 h2[10];
    #pragma unroll
    for (int j = 0; j < 10; ++j) {
        f32x2 a = sp(b2[j]);
        #pragma unroll
        for (int i = 0; i < 10; ++i) a = fma2(h1[i], sp(W2[i * 10 + j]), a);
        h2[j] = tanh2(a);
    }

    // Layer 3: [10] -> [10], leaky relu
    f32x2 h3[10];
    #pragma unroll
    for (int j = 0; j < 10; ++j) {
        f32x2 a = sp(b3[j]);
        #pragma unroll
        for (int i = 0; i < 10; ++i) a = fma2(h2[i], sp(W3[i * 10 + j]), a);
        h3[j] = lrelu2(a);
    }

    // Layer 4: [10] -> [1] (stays packed across elements; no horizontal add)
    f32x2 f = sp(b4[0]);
    #pragma unroll
    for (int i = 0; i < 10; ++i) f = fma2(h3[i], sp(W4[i]), f);

    f32x2 s = f * inv_r2;
    f32x2 ox = s * dx;
    f32x2 oy = s * dy;

    f32x4 o;
    o[0] = ox[0]; o[1] = oy[0]; o[2] = ox[1]; o[3] = oy[1];
    return o;
}

__global__ void __launch_bounds__(256) fused_mlp_kernel(
    const float* __restrict__ in,
    const float* __restrict__ W1, const float* __restrict__ b1,
    const float* __restrict__ W2, const float* __restrict__ b2,
    const float* __restrict__ W3, const float* __restrict__ b3,
    const float* __restrict__ W4, const float* __restrict__ b4,
    float* __restrict__ out, int npairs)
{
    int tid = blockIdx.x * blockDim.x + threadIdx.x;
    int p0 = 2 * tid;
    if (p0 >= npairs) return;
    int p1 = p0 + 1;
    bool v1 = (p1 < npairs);
    int q1 = v1 ? p1 : p0;

    const f32x4* in4 = reinterpret_cast<const f32x4*>(in);
    f32x4* out4 = reinterpret_cast<f32x4*>(out);

    // Issue ALL SIX loads before any compute: pair-1's loads hide under
    // pair-0's ~2300-cycle compute.
    f32x4 A0 = in4[3 * p0 + 0];
    f32x4 B0 = in4[3 * p0 + 1];
    f32x4 C0 = in4[3 * p0 + 2];
    f32x4 A1 = in4[3 * q1 + 0];
    f32x4 B1 = in4[3 * q1 + 1];
    f32x4 C1 = in4[3 * q1 + 2];

    out4[p0] = mlp_pair(A0, B0, C0, W1, b1, W2, b2, W3, b3, W4, b4);
    if (v1)
        out4[p1] = mlp_pair(A1, B1, C1, W1, b1, W2, b2, W3, b3, W4, b4);
}

extern "C" void kernel_launch(void* const* d_in, const int* in_sizes, int n_in,
                              void* d_out, int out_size, void* d_ws, size_t ws_size,
                              hipStream_t stream) {
    const float* in = (const float*)d_in[0];
    const float* W1 = (const float*)d_in[1];
    const float* b1 = (const float*)d_in[2];
    const float* W2 = (const float*)d_in[3];
    const float* b2 = (const float*)d_in[4];
    const float* W3 = (const float*)d_in[5];
    const float* b3 = (const float*)d_in[6];
    const float* W4 = (const float*)d_in[7];
    const float* b4 = (const float*)d_in[8];
    float* out = (float*)d_out;

    int npairs = out_size / 4;                    // 4 output floats per pair
    int nthreads = (npairs + 1) / 2;              // 2 pairs per thread
    int blocks = (nthreads + 255) / 256;
    fused_mlp_kernel<<<blocks, 256, 0, stream>>>(
        in, W1, b1, W2, b2, W3, b3, W4, b4, out, npairs);
}